// Round 11
// baseline (446.088 us; speedup 1.0000x reference)
//
#include <hip/hip_runtime.h>
#include <hip/hip_fp16.h>
#include <math.h>

#define NN 100000
#define NE 3200000
#define FIN 128
#define HD 64
#define TOUT 16
#define BSH 8                        // 256 nodes per bucket
#define NBUK ((NN + 255) / 256)      // 391 buckets
#define EPB 8192                     // edges per P1 block
#define CAP 12288                    // slots per bucket (mean 8192, ~45 sigma headroom)
#define NP1BLK ((NE + EPB - 1) / EPB)        // 391
#define NGEMM1 ((NN + 63) / 64)              // 1563
#define NPREP ((128 * 192) / 256)            // 96

// ---------------- init bucket cursors ----------------
__global__ __launch_bounds__(256) void k_init(int* __restrict__ bcur) {
  int t = blockIdx.x * 256 + threadIdx.x;
  if (t < NBUK) bcur[t] = t * CAP;
}

// ---------------- megaA: [p1 partition | layer-1 GEMM (unscaled fp16) | GRU weight prep] ----------------
__global__ __launch_bounds__(256) void k_megaA(const int* __restrict__ src, const int* __restrict__ dst,
                                               int* __restrict__ bcur, unsigned* __restrict__ packed,
                                               const float* __restrict__ x, const float* __restrict__ W1,
                                               __half* __restrict__ hwsH,
                                               const float* __restrict__ w_ih, const float* __restrict__ w_hh,
                                               float* __restrict__ Wcat) {
  __shared__ __align__(16) char smem[64 * 132 * 4];   // 33,792 B shared by branches
  int bid = blockIdx.x;
  int t = threadIdx.x;

  if (bid < NP1BLK) {
    // ---- P1: block-local histogram + run reservation (fixed-cap buckets) ----
    int* hist = (int*)smem;
    int* base = hist + NBUK;
    int e0 = bid * EPB;
    int e1 = e0 + EPB; if (e1 > NE) e1 = NE;
    for (int i = t; i < NBUK; i += 256) hist[i] = 0;
    __syncthreads();
    for (int e = e0 + t; e < e1; e += 256) atomicAdd(&hist[dst[e] >> BSH], 1);
    __syncthreads();
    for (int i = t; i < NBUK; i += 256) {
      int c = hist[i];
      base[i] = c ? atomicAdd(&bcur[i], c) : 0;
      hist[i] = 0;
    }
    __syncthreads();
    for (int e = e0 + t; e < e1; e += 256) {
      int d = dst[e];
      int b = d >> BSH;
      int p = base[b] + atomicAdd(&hist[b], 1);
      packed[p] = ((unsigned)(d & 255) << 17) | (unsigned)src[e];
    }
  } else if (bid < NP1BLK + NGEMM1) {
    // ---- layer-1 GEMM: hwsH[n,64] = half(x[n,128] @ W1[128,64]) (unscaled) ----
    constexpr int K = FIN, AS = FIN + 4;
    float* As = (float*)smem;
    int rowBase = (bid - NP1BLK) * 64;
    int nrows = NN - rowBase; if (nrows > 64) nrows = 64;
    for (int idx = t * 4; idx < 64 * K; idx += 1024) {
      int row = idx / K;
      int k = idx - row * K;
      float4 v = make_float4(0.f, 0.f, 0.f, 0.f);
      if (row < nrows) v = *(const float4*)(x + (size_t)(rowBase + row) * K + k);
      *(float4*)(&As[row * AS + k]) = v;
    }
    __syncthreads();
    int tx = t & 15, ty = t >> 4;
    int c0 = tx * 4, r0 = ty * 4;
    float acc[4][4] = {{0.f}};
    for (int k = 0; k < K; ++k) {
      float4 wv = *(const float4*)(W1 + (size_t)k * HD + c0);
      float wa[4] = {wv.x, wv.y, wv.z, wv.w};
#pragma unroll
      for (int i = 0; i < 4; ++i) {
        float a = As[(r0 + i) * AS + k];
#pragma unroll
        for (int j = 0; j < 4; ++j) acc[i][j] = fmaf(a, wa[j], acc[i][j]);
      }
    }
#pragma unroll
    for (int i = 0; i < 4; ++i) {
      int r = rowBase + r0 + i;
      if (r < NN) {
        __half2 p0 = __floats2half2_rn(acc[i][0], acc[i][1]);
        __half2 p1 = __floats2half2_rn(acc[i][2], acc[i][3]);
        __half2* cp = (__half2*)(hwsH + (size_t)r * HD + c0);
        cp[0] = p0;
        cp[1] = p1;
      }
    }
  } else {
    // ---- GRU weight prep: Wcat[k][192] ----
    int tt = (bid - NP1BLK - NGEMM1) * 256 + t;
    if (tt < 128 * 192) {
      int k = tt / 192, c = tt - k * 192;
      Wcat[tt] = (k < 64) ? w_ih[c * 64 + k] : w_hh[c * 64 + (k - 64)];
    }
  }
}

// ---------------- scan bucket totals -> global bucket bases ----------------
__global__ __launch_bounds__(512) void k_scanb(const int* __restrict__ bcur, int* __restrict__ bktBase,
                                               int* __restrict__ rowptr) {
  __shared__ int s[512];
  int t = threadIdx.x;
  int v = (t < NBUK) ? (bcur[t] - t * CAP) : 0;
  s[t] = v;
  __syncthreads();
  for (int off = 1; off < 512; off <<= 1) {
    int y = (t >= off) ? s[t - off] : 0;
    __syncthreads();
    s[t] += y;
    __syncthreads();
  }
  if (t < NBUK) bktBase[t] = s[t] - v;
  if (t == 0) rowptr[NN] = NE;
}

// ---------------- P2: per-bucket degree histogram + local scan + rowptr/dinv + CSR place ----------------
__global__ __launch_bounds__(256) void k_p2big(const unsigned* __restrict__ packed, const int* __restrict__ bcur,
                                               const int* __restrict__ bktBase, int* __restrict__ rowptr,
                                               float* __restrict__ dinv, int* __restrict__ csr_src) {
  __shared__ int degl[256];
  __shared__ int sc[256];
  __shared__ int cur[256];
  int b = blockIdx.x, t = threadIdx.x;
  int pbase = b * CAP;
  int cnt = bcur[b] - pbase;

  degl[t] = 0;
  __syncthreads();
  for (int i = t; i < cnt; i += 256) {
    unsigned v = packed[pbase + i];
    atomicAdd(&degl[v >> 17], 1);
  }
  __syncthreads();
  int dv = degl[t];
  sc[t] = dv;
  __syncthreads();
  for (int off = 1; off < 256; off <<= 1) {
    int y = (t >= off) ? sc[t - off] : 0;
    __syncthreads();
    sc[t] += y;
    __syncthreads();
  }
  int gpos = bktBase[b] + (sc[t] - dv);
  int node = (b << BSH) + t;
  if (node < NN) {
    rowptr[node] = gpos;
    dinv[node] = 1.0f / sqrtf((float)dv + 1.0f);   // +1 self-loop
  }
  cur[t] = gpos;
  __syncthreads();
  for (int i = t; i < cnt; i += 256) {
    unsigned pv = packed[pbase + i];
    int pos = atomicAdd(&cur[pv >> 17], 1);
    csr_src[pos] = (int)(pv & 0x1FFFFu);
  }
}

// ---------------- layer-2 GEMM: hwsH[n,64] = half(A[n,64] @ W2[64,64]) (unscaled) ----------------
__global__ __launch_bounds__(256) void k_gemmh64(const float* __restrict__ A, const float* __restrict__ W,
                                                 __half* __restrict__ Ch) {
  constexpr int K = HD, AS = HD + 4;
  __shared__ float As[64 * AS];
  int tid = threadIdx.x;
  int rowBase = blockIdx.x * 64;
  int nrows = NN - rowBase; if (nrows > 64) nrows = 64;

  for (int idx = tid * 4; idx < 64 * K; idx += 1024) {
    int row = idx / K;
    int k = idx - row * K;
    float4 v = make_float4(0.f, 0.f, 0.f, 0.f);
    if (row < nrows) v = *(const float4*)(A + (size_t)(rowBase + row) * K + k);
    *(float4*)(&As[row * AS + k]) = v;
  }
  __syncthreads();

  int tx = tid & 15, ty = tid >> 4;
  int c0 = tx * 4, r0 = ty * 4;
  float acc[4][4] = {{0.f}};
  for (int k = 0; k < K; ++k) {
    float4 wv = *(const float4*)(W + (size_t)k * HD + c0);
    float wa[4] = {wv.x, wv.y, wv.z, wv.w};
#pragma unroll
    for (int i = 0; i < 4; ++i) {
      float a = As[(r0 + i) * AS + k];
#pragma unroll
      for (int j = 0; j < 4; ++j) acc[i][j] = fmaf(a, wa[j], acc[i][j]);
    }
  }
#pragma unroll
  for (int i = 0; i < 4; ++i) {
    int r = rowBase + r0 + i;
    if (r < NN) {
      __half2 p0 = __floats2half2_rn(acc[i][0], acc[i][1]);
      __half2 p1 = __floats2half2_rn(acc[i][2], acc[i][3]);
      __half2* cp = (__half2*)(Ch + (size_t)r * HD + c0);
      cp[0] = p0;
      cp[1] = p1;
    }
  }
}

// ---------------- gather v3 (fp16 table, 16B/lane, 8 edges/wave in flight, per-edge dinv[s]) ----------------
// h[d] = relu(dinv[d]*(dinv[d]*hw[d] + sum_e dinv[s]*hw[s]) + b)
__global__ __launch_bounds__(256) void k_gather(const __half* __restrict__ hws, const int* __restrict__ rowptr,
                                                const int* __restrict__ csr_src, const float* __restrict__ dinv,
                                                const float* __restrict__ b, float* __restrict__ h) {
  int node = blockIdx.x * 4 + (threadIdx.x >> 6);
  if (node >= NN) return;
  int lane = threadIdx.x & 63;
  int f8  = lane & 7;     // 16B segment (features 8*f8 .. 8*f8+7)
  int grp = lane >> 3;    // 0..7: edge subgroup
  int beg = rowptr[node], end = rowptr[node + 1];
  const uint4* hw4 = (const uint4*)hws;   // one row = 8 uint4
  float acc[8] = {0.f, 0.f, 0.f, 0.f, 0.f, 0.f, 0.f, 0.f};

  for (int base = beg; base < end; base += 64) {
    int m = end - base; if (m > 64) m = 64;
    int myS = 0; float myD = 0.f;
    if (lane < m) { myS = csr_src[base + lane]; myD = dinv[myS]; }
    for (int i = 0; i < m; i += 8) {
      int idx = i + grp;
      int sel = idx < m ? idx : 0;
      int s = __shfl(myS, sel);
      float dv = __shfl(myD, sel);
      if (idx < m) {
        uint4 u = hw4[(size_t)s * 8 + f8];
        float2 p0 = __half22float2(*(__half2*)&u.x);
        float2 p1 = __half22float2(*(__half2*)&u.y);
        float2 p2 = __half22float2(*(__half2*)&u.z);
        float2 p3 = __half22float2(*(__half2*)&u.w);
        acc[0] = fmaf(dv, p0.x, acc[0]); acc[1] = fmaf(dv, p0.y, acc[1]);
        acc[2] = fmaf(dv, p1.x, acc[2]); acc[3] = fmaf(dv, p1.y, acc[3]);
        acc[4] = fmaf(dv, p2.x, acc[4]); acc[5] = fmaf(dv, p2.y, acc[5]);
        acc[6] = fmaf(dv, p3.x, acc[6]); acc[7] = fmaf(dv, p3.y, acc[7]);
      }
    }
  }

  // reduce across the 8 edge subgroups (lane bits 3,4,5)
#pragma unroll
  for (int j = 0; j < 8; ++j) {
    acc[j] += __shfl_xor(acc[j], 8);
    acc[j] += __shfl_xor(acc[j], 16);
    acc[j] += __shfl_xor(acc[j], 32);
  }

  if (lane < 8) {
    float dn = dinv[node];
    uint4 u = hw4[(size_t)node * 8 + f8];            // self-loop (unscaled)
    float2 p0 = __half22float2(*(__half2*)&u.x);
    float2 p1 = __half22float2(*(__half2*)&u.y);
    float2 p2 = __half22float2(*(__half2*)&u.z);
    float2 p3 = __half22float2(*(__half2*)&u.w);
    acc[0] = fmaf(dn, p0.x, acc[0]); acc[1] = fmaf(dn, p0.y, acc[1]);
    acc[2] = fmaf(dn, p1.x, acc[2]); acc[3] = fmaf(dn, p1.y, acc[3]);
    acc[4] = fmaf(dn, p2.x, acc[4]); acc[5] = fmaf(dn, p2.y, acc[5]);
    acc[6] = fmaf(dn, p3.x, acc[6]); acc[7] = fmaf(dn, p3.y, acc[7]);
    float4 bb0 = *(const float4*)(b + f8 * 8);
    float4 bb1 = *(const float4*)(b + f8 * 8 + 4);
    float4 o0, o1;
    o0.x = fmaxf(fmaf(dn, acc[0], bb0.x), 0.f);
    o0.y = fmaxf(fmaf(dn, acc[1], bb0.y), 0.f);
    o0.z = fmaxf(fmaf(dn, acc[2], bb0.z), 0.f);
    o0.w = fmaxf(fmaf(dn, acc[3], bb0.w), 0.f);
    o1.x = fmaxf(fmaf(dn, acc[4], bb1.x), 0.f);
    o1.y = fmaxf(fmaf(dn, acc[5], bb1.y), 0.f);
    o1.z = fmaxf(fmaf(dn, acc[6], bb1.z), 0.f);
    o1.w = fmaxf(fmaf(dn, acc[7], bb1.w), 0.f);
    *(float4*)(h + (size_t)node * HD + f8 * 8) = o0;
    *(float4*)(h + (size_t)node * HD + f8 * 8 + 4) = o1;
  }
}

// ---------------- fused GRU v4: 128 rows/block, scalar weight stream, lane = 2 rows ----------------
// A-tile k-major: As2[k][128] (h in k=0..63, h0 in k=64..127), 64KB LDS.
// Per kk per wave: 2 ds_read_b32 + 48 scalar weights + 96 FMA.
__global__ __launch_bounds__(256) void k_grufused(const float* __restrict__ h, const float* __restrict__ prev,
                                                  const float* __restrict__ Wcat,
                                                  const float* __restrict__ bih, const float* __restrict__ bhh,
                                                  const float* __restrict__ Wp, const float* __restrict__ bp,
                                                  float* __restrict__ hnew, float* __restrict__ out) {
  __shared__ float As2[128 * 128];   // 65,536 B
  int tid = threadIdx.x;
  int rowBase = blockIdx.x * 128;
  int nrows = NN - rowBase; if (nrows > 128) nrows = 128;

  // stage k-major: h -> k 0..63, prev -> k 64..127 (zero-fill OOB rows)
  for (int idx = tid * 4; idx < 128 * 128; idx += 1024) {
    int r = idx >> 7, k = idx & 127;
    float4 v = make_float4(0.f, 0.f, 0.f, 0.f);
    if (r < nrows) {
      if (k < 64) v = *(const float4*)(h + (size_t)(rowBase + r) * HD + k);
      else        v = *(const float4*)(prev + (size_t)(rowBase + r) * HD + (k - 64));
    }
    As2[(k + 0) * 128 + r] = v.x;
    As2[(k + 1) * 128 + r] = v.y;
    As2[(k + 2) * 128 + r] = v.z;
    As2[(k + 3) * 128 + r] = v.w;
  }
  __syncthreads();

  int lane = tid & 63;
  int wid = __builtin_amdgcn_readfirstlane(tid >> 6);
  int cbase = wid * 16;

  float aR0[16] = {0.f}, aZ0[16] = {0.f}, aNi0[16] = {0.f}, aNh0[16] = {0.f};
  float aR1[16] = {0.f}, aZ1[16] = {0.f}, aNi1[16] = {0.f}, aNh1[16] = {0.f};

  for (int kk = 0; kk < 64; ++kk) {
    float a0 = As2[kk * 128 + lane];
    float a1 = As2[kk * 128 + lane + 64];
    const float* Wk = Wcat + kk * 192 + cbase;
#pragma unroll
    for (int j = 0; j < 16; ++j) {
      float wr = Wk[j], wz = Wk[64 + j], wn = Wk[128 + j];
      aR0[j]  = fmaf(a0, wr, aR0[j]);  aR1[j]  = fmaf(a1, wr, aR1[j]);
      aZ0[j]  = fmaf(a0, wz, aZ0[j]);  aZ1[j]  = fmaf(a1, wz, aZ1[j]);
      aNi0[j] = fmaf(a0, wn, aNi0[j]); aNi1[j] = fmaf(a1, wn, aNi1[j]);
    }
  }
  for (int kk = 64; kk < 128; ++kk) {
    float a0 = As2[kk * 128 + lane];
    float a1 = As2[kk * 128 + lane + 64];
    const float* Wk = Wcat + kk * 192 + cbase;
#pragma unroll
    for (int j = 0; j < 16; ++j) {
      float wr = Wk[j], wz = Wk[64 + j], wn = Wk[128 + j];
      aR0[j]  = fmaf(a0, wr, aR0[j]);  aR1[j]  = fmaf(a1, wr, aR1[j]);
      aZ0[j]  = fmaf(a0, wz, aZ0[j]);  aZ1[j]  = fmaf(a1, wz, aZ1[j]);
      aNh0[j] = fmaf(a0, wn, aNh0[j]); aNh1[j] = fmaf(a1, wn, aNh1[j]);
    }
  }

  // epilogue: gates + hnew for rows lane and lane+64
  float hn0[16], hn1[16];
#pragma unroll
  for (int j = 0; j < 16; ++j) {
    float bi_r = bih[cbase + j],       bh_r = bhh[cbase + j];
    float bi_z = bih[64 + cbase + j],  bh_z = bhh[64 + cbase + j];
    float bi_n = bih[128 + cbase + j], bh_n = bhh[128 + cbase + j];
    float h00 = As2[(64 + cbase + j) * 128 + lane];
    float h01 = As2[(64 + cbase + j) * 128 + lane + 64];
    float rg0 = 1.f / (1.f + expf(-(aR0[j] + bi_r + bh_r)));
    float rg1 = 1.f / (1.f + expf(-(aR1[j] + bi_r + bh_r)));
    float zg0 = 1.f / (1.f + expf(-(aZ0[j] + bi_z + bh_z)));
    float zg1 = 1.f / (1.f + expf(-(aZ1[j] + bi_z + bh_z)));
    float nc0 = tanhf(aNi0[j] + bi_n + rg0 * (aNh0[j] + bh_n));
    float nc1 = tanhf(aNi1[j] + bi_n + rg1 * (aNh1[j] + bh_n));
    hn0[j] = (1.f - zg0) * nc0 + zg0 * h00;
    hn1[j] = (1.f - zg1) * nc1 + zg1 * h01;
  }
  if (rowBase + lane < NN) {
#pragma unroll
    for (int j4 = 0; j4 < 4; ++j4)
      *(float4*)(hnew + (size_t)(rowBase + lane) * HD + cbase + j4 * 4) =
          make_float4(hn0[j4 * 4], hn0[j4 * 4 + 1], hn0[j4 * 4 + 2], hn0[j4 * 4 + 3]);
  }
  if (rowBase + lane + 64 < NN) {
#pragma unroll
    for (int j4 = 0; j4 < 4; ++j4)
      *(float4*)(hnew + (size_t)(rowBase + lane + 64) * HD + cbase + j4 * 4) =
          make_float4(hn1[j4 * 4], hn1[j4 * 4 + 1], hn1[j4 * 4 + 2], hn1[j4 * 4 + 3]);
  }

  // readout partials: pt[t] = sum_j hn[j] * Wp[cbase+j][t]
  float pt0[16] = {0.f}, pt1[16] = {0.f};
#pragma unroll
  for (int j = 0; j < 16; ++j) {
    const float* wp = Wp + (size_t)(cbase + j) * TOUT;
#pragma unroll
    for (int t = 0; t < 16; ++t) {
      pt0[t] = fmaf(hn0[j], wp[t], pt0[t]);
      pt1[t] = fmaf(hn1[j], wp[t], pt1[t]);
    }
  }

  __syncthreads();                  // As2 fully consumed; reuse as exchange buffer
  float* ex = As2;                  // part[w][r(128)][17]
#pragma unroll
  for (int t = 0; t < 16; ++t) {
    ex[wid * 2176 + lane * 17 + t] = pt0[t];
    ex[wid * 2176 + (lane + 64) * 17 + t] = pt1[t];
  }
  __syncthreads();

  int orow = tid >> 1;
  int t8 = (tid & 1) * 8;
  if (rowBase + orow < NN) {
    float s[8];
#pragma unroll
    for (int i = 0; i < 8; ++i) s[i] = bp[t8 + i];
#pragma unroll
    for (int w = 0; w < 4; ++w)
#pragma unroll
      for (int i = 0; i < 8; ++i) s[i] += ex[w * 2176 + orow * 17 + t8 + i];
    *(float4*)(out + (size_t)(rowBase + orow) * TOUT + t8) = make_float4(s[0], s[1], s[2], s[3]);
    *(float4*)(out + (size_t)(rowBase + orow) * TOUT + t8 + 4) = make_float4(s[4], s[5], s[6], s[7]);
  }
}

extern "C" void kernel_launch(void* const* d_in, const int* in_sizes, int n_in,
                              void* d_out, int out_size, void* d_ws, size_t ws_size,
                              hipStream_t stream) {
  const float* x    = (const float*)d_in[0];
  const int*   ei   = (const int*)d_in[1];
  const float* prev = (const float*)d_in[2];
  const float* W1   = (const float*)d_in[3];
  const float* b1   = (const float*)d_in[4];
  const float* W2   = (const float*)d_in[5];
  const float* b2   = (const float*)d_in[6];
  const float* w_ih = (const float*)d_in[7];
  const float* w_hh = (const float*)d_in[8];
  const float* b_ih = (const float*)d_in[9];
  const float* b_hh = (const float*)d_in[10];
  const float* Wp   = (const float*)d_in[11];
  const float* bp   = (const float*)d_in[12];

  float* out  = (float*)d_out;                 // [NN,16]
  float* hnew = out + (size_t)NN * TOUT;       // [NN,64]

  char* ws = (char*)d_ws;
  float*    dinv    = (float*)(ws + 0);                    // 400,000
  int*      rowptr  = (int*)(ws + 400000);                 // 400,064
  int*      bcur    = (int*)(ws + 800064);                 // 1,564
  int*      bktBase = (int*)(ws + 801664);                 // 1,564
  int*      csr_src = (int*)(ws + 803264);                 // 12,800,000
  __half*   hwsH    = (__half*)(ws + 13603264);            // 12,800,000
  float*    bufB    = (float*)(ws + 26403264);             // 25,600,000 (packed u32 alias; CAP*NBUK*4 = 19.2MB)
  float*    bufC    = (float*)(ws + 52003264);             // 25,600,000
  float*    Wcat    = (float*)(ws + 77603264);             // 98,304
  unsigned* packed  = (unsigned*)bufB;

  const int* srcA = ei;
  const int* dstA = ei + NE;

  // ---- CSR build overlapped with layer-1 GEMM + GRU weight prep ----
  k_init<<<(NBUK + 255) / 256, 256, 0, stream>>>(bcur);
  k_megaA<<<NP1BLK + NGEMM1 + NPREP, 256, 0, stream>>>(srcA, dstA, bcur, packed,
                                                       x, W1, hwsH, w_ih, w_hh, Wcat);
  k_scanb<<<1, 512, 0, stream>>>(bcur, bktBase, rowptr);
  k_p2big<<<NBUK, 256, 0, stream>>>(packed, bcur, bktBase, rowptr, dinv, csr_src);

  // ---- GCN layer 1 gather ----
  k_gather<<<(NN + 3) / 4, 256, 0, stream>>>(hwsH, rowptr, csr_src, dinv, b1, bufC);

  // ---- GCN layer 2 ----
  k_gemmh64<<<(NN + 63) / 64, 256, 0, stream>>>(bufC, W2, hwsH);
  k_gather<<<(NN + 3) / 4, 256, 0, stream>>>(hwsH, rowptr, csr_src, dinv, b2, bufC);

  // ---- fused GRU (128-row scalar-weight GEMM + gates + readout) ----
  k_grufused<<<(NN + 127) / 128, 256, 0, stream>>>(bufC, prev, Wcat, b_ih, b_hh, Wp, bp, hnew, out);
}

// Round 12
// 395.622 us; speedup vs baseline: 1.1276x; 1.1276x over previous
//
#include <hip/hip_runtime.h>
#include <hip/hip_fp16.h>
#include <math.h>

#define NN 100000
#define NE 3200000
#define FIN 128
#define HD 64
#define TOUT 16
#define BSH 8                        // 256 nodes per bucket
#define NBUK ((NN + 255) / 256)      // 391 buckets
#define EPB 8192                     // edges per P1 block
#define CAP 12288                    // slots per bucket (mean 8192, ~45 sigma headroom)
#define NP1BLK ((NE + EPB - 1) / EPB)        // 391
#define NGEMM1 ((NN + 63) / 64)              // 1563
#define NPREP ((128 * 192) / 256)            // 96

// ---------------- init bucket cursors ----------------
__global__ __launch_bounds__(256) void k_init(int* __restrict__ bcur) {
  int t = blockIdx.x * 256 + threadIdx.x;
  if (t < NBUK) bcur[t] = t * CAP;
}

// ---------------- megaA: [p1 partition | layer-1 GEMM (unscaled fp16) | GRU weight prep] ----------------
__global__ __launch_bounds__(256) void k_megaA(const int* __restrict__ src, const int* __restrict__ dst,
                                               int* __restrict__ bcur, unsigned* __restrict__ packed,
                                               const float* __restrict__ x, const float* __restrict__ W1,
                                               __half* __restrict__ hwsH,
                                               const float* __restrict__ w_ih, const float* __restrict__ w_hh,
                                               float* __restrict__ Wcat) {
  __shared__ __align__(16) char smem[64 * 132 * 4];   // 33,792 B shared by branches
  int bid = blockIdx.x;
  int t = threadIdx.x;

  if (bid < NP1BLK) {
    // ---- P1: block-local histogram + run reservation (fixed-cap buckets) ----
    int* hist = (int*)smem;
    int* base = hist + NBUK;
    int e0 = bid * EPB;
    int e1 = e0 + EPB; if (e1 > NE) e1 = NE;
    for (int i = t; i < NBUK; i += 256) hist[i] = 0;
    __syncthreads();
    for (int e = e0 + t; e < e1; e += 256) atomicAdd(&hist[dst[e] >> BSH], 1);
    __syncthreads();
    for (int i = t; i < NBUK; i += 256) {
      int c = hist[i];
      base[i] = c ? atomicAdd(&bcur[i], c) : 0;
      hist[i] = 0;
    }
    __syncthreads();
    for (int e = e0 + t; e < e1; e += 256) {
      int d = dst[e];
      int b = d >> BSH;
      int p = base[b] + atomicAdd(&hist[b], 1);
      packed[p] = ((unsigned)(d & 255) << 17) | (unsigned)src[e];
    }
  } else if (bid < NP1BLK + NGEMM1) {
    // ---- layer-1 GEMM: hwsH[n,64] = half(x[n,128] @ W1[128,64]) (unscaled) ----
    constexpr int K = FIN, AS = FIN + 4;
    float* As = (float*)smem;
    int rowBase = (bid - NP1BLK) * 64;
    int nrows = NN - rowBase; if (nrows > 64) nrows = 64;
    for (int idx = t * 4; idx < 64 * K; idx += 1024) {
      int row = idx / K;
      int k = idx - row * K;
      float4 v = make_float4(0.f, 0.f, 0.f, 0.f);
      if (row < nrows) v = *(const float4*)(x + (size_t)(rowBase + row) * K + k);
      *(float4*)(&As[row * AS + k]) = v;
    }
    __syncthreads();
    int tx = t & 15, ty = t >> 4;
    int c0 = tx * 4, r0 = ty * 4;
    float acc[4][4] = {{0.f}};
    for (int k = 0; k < K; ++k) {
      float4 wv = *(const float4*)(W1 + (size_t)k * HD + c0);
      float wa[4] = {wv.x, wv.y, wv.z, wv.w};
#pragma unroll
      for (int i = 0; i < 4; ++i) {
        float a = As[(r0 + i) * AS + k];
#pragma unroll
        for (int j = 0; j < 4; ++j) acc[i][j] = fmaf(a, wa[j], acc[i][j]);
      }
    }
#pragma unroll
    for (int i = 0; i < 4; ++i) {
      int r = rowBase + r0 + i;
      if (r < NN) {
        __half2 p0 = __floats2half2_rn(acc[i][0], acc[i][1]);
        __half2 p1 = __floats2half2_rn(acc[i][2], acc[i][3]);
        __half2* cp = (__half2*)(hwsH + (size_t)r * HD + c0);
        cp[0] = p0;
        cp[1] = p1;
      }
    }
  } else {
    // ---- GRU weight prep: Wcat[k][192] ----
    int tt = (bid - NP1BLK - NGEMM1) * 256 + t;
    if (tt < 128 * 192) {
      int k = tt / 192, c = tt - k * 192;
      Wcat[tt] = (k < 64) ? w_ih[c * 64 + k] : w_hh[c * 64 + (k - 64)];
    }
  }
}

// ---------------- scan bucket totals -> global bucket bases ----------------
__global__ __launch_bounds__(512) void k_scanb(const int* __restrict__ bcur, int* __restrict__ bktBase,
                                               int* __restrict__ rowptr) {
  __shared__ int s[512];
  int t = threadIdx.x;
  int v = (t < NBUK) ? (bcur[t] - t * CAP) : 0;
  s[t] = v;
  __syncthreads();
  for (int off = 1; off < 512; off <<= 1) {
    int y = (t >= off) ? s[t - off] : 0;
    __syncthreads();
    s[t] += y;
    __syncthreads();
  }
  if (t < NBUK) bktBase[t] = s[t] - v;
  if (t == 0) rowptr[NN] = NE;
}

// ---------------- P2: per-bucket degree histogram + local scan + rowptr/dinv + CSR place ----------------
__global__ __launch_bounds__(256) void k_p2big(const unsigned* __restrict__ packed, const int* __restrict__ bcur,
                                               const int* __restrict__ bktBase, int* __restrict__ rowptr,
                                               float* __restrict__ dinv, int* __restrict__ csr_src) {
  __shared__ int degl[256];
  __shared__ int sc[256];
  __shared__ int cur[256];
  int b = blockIdx.x, t = threadIdx.x;
  int pbase = b * CAP;
  int cnt = bcur[b] - pbase;

  degl[t] = 0;
  __syncthreads();
  for (int i = t; i < cnt; i += 256) {
    unsigned v = packed[pbase + i];
    atomicAdd(&degl[v >> 17], 1);
  }
  __syncthreads();
  int dv = degl[t];
  sc[t] = dv;
  __syncthreads();
  for (int off = 1; off < 256; off <<= 1) {
    int y = (t >= off) ? sc[t - off] : 0;
    __syncthreads();
    sc[t] += y;
    __syncthreads();
  }
  int gpos = bktBase[b] + (sc[t] - dv);
  int node = (b << BSH) + t;
  if (node < NN) {
    rowptr[node] = gpos;
    dinv[node] = 1.0f / sqrtf((float)dv + 1.0f);   // +1 self-loop
  }
  cur[t] = gpos;
  __syncthreads();
  for (int i = t; i < cnt; i += 256) {
    unsigned pv = packed[pbase + i];
    int pos = atomicAdd(&cur[pv >> 17], 1);
    csr_src[pos] = (int)(pv & 0x1FFFFu);
  }
}

// ---------------- layer-2 GEMM: hwsH[n,64] = half(A[n,64] @ W2[64,64]) (unscaled) ----------------
__global__ __launch_bounds__(256) void k_gemmh64(const float* __restrict__ A, const float* __restrict__ W,
                                                 __half* __restrict__ Ch) {
  constexpr int K = HD, AS = HD + 4;
  __shared__ float As[64 * AS];
  int tid = threadIdx.x;
  int rowBase = blockIdx.x * 64;
  int nrows = NN - rowBase; if (nrows > 64) nrows = 64;

  for (int idx = tid * 4; idx < 64 * K; idx += 1024) {
    int row = idx / K;
    int k = idx - row * K;
    float4 v = make_float4(0.f, 0.f, 0.f, 0.f);
    if (row < nrows) v = *(const float4*)(A + (size_t)(rowBase + row) * K + k);
    *(float4*)(&As[row * AS + k]) = v;
  }
  __syncthreads();

  int tx = tid & 15, ty = tid >> 4;
  int c0 = tx * 4, r0 = ty * 4;
  float acc[4][4] = {{0.f}};
  for (int k = 0; k < K; ++k) {
    float4 wv = *(const float4*)(W + (size_t)k * HD + c0);
    float wa[4] = {wv.x, wv.y, wv.z, wv.w};
#pragma unroll
    for (int i = 0; i < 4; ++i) {
      float a = As[(r0 + i) * AS + k];
#pragma unroll
      for (int j = 0; j < 4; ++j) acc[i][j] = fmaf(a, wa[j], acc[i][j]);
    }
  }
#pragma unroll
  for (int i = 0; i < 4; ++i) {
    int r = rowBase + r0 + i;
    if (r < NN) {
      __half2 p0 = __floats2half2_rn(acc[i][0], acc[i][1]);
      __half2 p1 = __floats2half2_rn(acc[i][2], acc[i][3]);
      __half2* cp = (__half2*)(Ch + (size_t)r * HD + c0);
      cp[0] = p0;
      cp[1] = p1;
    }
  }
}

// ---------------- gather v3 (fp16 table, 16B/lane, 8 edges/wave in flight, per-edge dinv[s]) ----------------
__global__ __launch_bounds__(256) void k_gather(const __half* __restrict__ hws, const int* __restrict__ rowptr,
                                                const int* __restrict__ csr_src, const float* __restrict__ dinv,
                                                const float* __restrict__ b, float* __restrict__ h) {
  int node = blockIdx.x * 4 + (threadIdx.x >> 6);
  if (node >= NN) return;
  int lane = threadIdx.x & 63;
  int f8  = lane & 7;     // 16B segment (features 8*f8 .. 8*f8+7)
  int grp = lane >> 3;    // 0..7: edge subgroup
  int beg = rowptr[node], end = rowptr[node + 1];
  const uint4* hw4 = (const uint4*)hws;   // one row = 8 uint4
  float acc[8] = {0.f, 0.f, 0.f, 0.f, 0.f, 0.f, 0.f, 0.f};

  for (int base = beg; base < end; base += 64) {
    int m = end - base; if (m > 64) m = 64;
    int myS = 0; float myD = 0.f;
    if (lane < m) { myS = csr_src[base + lane]; myD = dinv[myS]; }
    for (int i = 0; i < m; i += 8) {
      int idx = i + grp;
      int sel = idx < m ? idx : 0;
      int s = __shfl(myS, sel);
      float dv = __shfl(myD, sel);
      if (idx < m) {
        uint4 u = hw4[(size_t)s * 8 + f8];
        float2 p0 = __half22float2(*(__half2*)&u.x);
        float2 p1 = __half22float2(*(__half2*)&u.y);
        float2 p2 = __half22float2(*(__half2*)&u.z);
        float2 p3 = __half22float2(*(__half2*)&u.w);
        acc[0] = fmaf(dv, p0.x, acc[0]); acc[1] = fmaf(dv, p0.y, acc[1]);
        acc[2] = fmaf(dv, p1.x, acc[2]); acc[3] = fmaf(dv, p1.y, acc[3]);
        acc[4] = fmaf(dv, p2.x, acc[4]); acc[5] = fmaf(dv, p2.y, acc[5]);
        acc[6] = fmaf(dv, p3.x, acc[6]); acc[7] = fmaf(dv, p3.y, acc[7]);
      }
    }
  }

#pragma unroll
  for (int j = 0; j < 8; ++j) {
    acc[j] += __shfl_xor(acc[j], 8);
    acc[j] += __shfl_xor(acc[j], 16);
    acc[j] += __shfl_xor(acc[j], 32);
  }

  if (lane < 8) {
    float dn = dinv[node];
    uint4 u = hw4[(size_t)node * 8 + f8];            // self-loop (unscaled)
    float2 p0 = __half22float2(*(__half2*)&u.x);
    float2 p1 = __half22float2(*(__half2*)&u.y);
    float2 p2 = __half22float2(*(__half2*)&u.z);
    float2 p3 = __half22float2(*(__half2*)&u.w);
    acc[0] = fmaf(dn, p0.x, acc[0]); acc[1] = fmaf(dn, p0.y, acc[1]);
    acc[2] = fmaf(dn, p1.x, acc[2]); acc[3] = fmaf(dn, p1.y, acc[3]);
    acc[4] = fmaf(dn, p2.x, acc[4]); acc[5] = fmaf(dn, p2.y, acc[5]);
    acc[6] = fmaf(dn, p3.x, acc[6]); acc[7] = fmaf(dn, p3.y, acc[7]);
    float4 bb0 = *(const float4*)(b + f8 * 8);
    float4 bb1 = *(const float4*)(b + f8 * 8 + 4);
    float4 o0, o1;
    o0.x = fmaxf(fmaf(dn, acc[0], bb0.x), 0.f);
    o0.y = fmaxf(fmaf(dn, acc[1], bb0.y), 0.f);
    o0.z = fmaxf(fmaf(dn, acc[2], bb0.z), 0.f);
    o0.w = fmaxf(fmaf(dn, acc[3], bb0.w), 0.f);
    o1.x = fmaxf(fmaf(dn, acc[4], bb1.x), 0.f);
    o1.y = fmaxf(fmaf(dn, acc[5], bb1.y), 0.f);
    o1.z = fmaxf(fmaf(dn, acc[6], bb1.z), 0.f);
    o1.w = fmaxf(fmaf(dn, acc[7], bb1.w), 0.f);
    *(float4*)(h + (size_t)node * HD + f8 * 8) = o0;
    *(float4*)(h + (size_t)node * HD + f8 * 8 + 4) = o1;
  }
}

// ---------------- fused GRU v3.5: 64 rows, scalar weight stream, 8-wide a-prefetch ----------------
// A-tile k-major: As2[k][64] (h in k=0..63, h0 in k=64..127), 32KB LDS.
// Per 8-kk chunk: 8 independent ds_read_b32 (pipelined), then 384 FMAs on scalar weights.
__global__ __launch_bounds__(256) void k_grufused(const float* __restrict__ h, const float* __restrict__ prev,
                                                  const float* __restrict__ Wcat,
                                                  const float* __restrict__ bih, const float* __restrict__ bhh,
                                                  const float* __restrict__ Wp, const float* __restrict__ bp,
                                                  float* __restrict__ hnew, float* __restrict__ out) {
  __shared__ float As2[128 * 64];   // 32,768 B
  int tid = threadIdx.x;
  int rowBase = blockIdx.x * 64;
  int nrows = NN - rowBase; if (nrows > 64) nrows = 64;
  int row = tid & 63;               // lane = row
  int c4base = tid >> 6;            // 0..3

  // stage k-major: h -> k 0..63, prev -> k 64..127 (conflict-free: bank = row%32)
  for (int c4 = c4base; c4 < 32; c4 += 4) {
    float4 v = make_float4(0.f, 0.f, 0.f, 0.f);
    if (row < nrows) {
      if (c4 < 16) v = *(const float4*)(h + (size_t)(rowBase + row) * HD + c4 * 4);
      else         v = *(const float4*)(prev + (size_t)(rowBase + row) * HD + (c4 - 16) * 4);
    }
    int k0 = c4 * 4;
    As2[(k0 + 0) * 64 + row] = v.x;
    As2[(k0 + 1) * 64 + row] = v.y;
    As2[(k0 + 2) * 64 + row] = v.z;
    As2[(k0 + 3) * 64 + row] = v.w;
  }
  __syncthreads();

  int wid = __builtin_amdgcn_readfirstlane(tid >> 6);   // force wave-uniform
  int cbase = wid * 16;                                 // this wave's 16 output cols

  float aR[16] = {0.f}, aZ[16] = {0.f}, aNi[16] = {0.f}, aNh[16] = {0.f};

  // phase 1: k<64 (A = h); n-gate -> aNi
  for (int kk = 0; kk < 64; kk += 8) {
    float a8[8];
#pragma unroll
    for (int u = 0; u < 8; ++u) a8[u] = As2[(kk + u) * 64 + row];
#pragma unroll
    for (int u = 0; u < 8; ++u) {
      const float* Wk = Wcat + (kk + u) * 192 + cbase;  // wave-uniform -> s_load
#pragma unroll
      for (int j = 0; j < 16; ++j) {
        aR[j]  = fmaf(a8[u], Wk[j], aR[j]);
        aZ[j]  = fmaf(a8[u], Wk[64 + j], aZ[j]);
        aNi[j] = fmaf(a8[u], Wk[128 + j], aNi[j]);
      }
    }
  }
  // phase 2: k>=64 (A = h0); n-gate -> aNh
  for (int kk = 64; kk < 128; kk += 8) {
    float a8[8];
#pragma unroll
    for (int u = 0; u < 8; ++u) a8[u] = As2[(kk + u) * 64 + row];
#pragma unroll
    for (int u = 0; u < 8; ++u) {
      const float* Wk = Wcat + (kk + u) * 192 + cbase;
#pragma unroll
      for (int j = 0; j < 16; ++j) {
        aR[j]  = fmaf(a8[u], Wk[j], aR[j]);
        aZ[j]  = fmaf(a8[u], Wk[64 + j], aZ[j]);
        aNh[j] = fmaf(a8[u], Wk[128 + j], aNh[j]);
      }
    }
  }

  // epilogue: gates + hnew (all lane-local; h0 from LDS)
  float hn[16];
#pragma unroll
  for (int j = 0; j < 16; ++j) {
    float h0v = As2[(64 + cbase + j) * 64 + row];
    float rg = 1.f / (1.f + expf(-(aR[j] + bih[cbase + j] + bhh[cbase + j])));
    float zg = 1.f / (1.f + expf(-(aZ[j] + bih[64 + cbase + j] + bhh[64 + cbase + j])));
    float nc = tanhf(aNi[j] + bih[128 + cbase + j] + rg * (aNh[j] + bhh[128 + cbase + j]));
    hn[j] = (1.f - zg) * nc + zg * h0v;
  }
  if (row < nrows) {
#pragma unroll
    for (int j4 = 0; j4 < 4; ++j4)
      *(float4*)(hnew + (size_t)(rowBase + row) * HD + cbase + j4 * 4) =
          make_float4(hn[j4 * 4], hn[j4 * 4 + 1], hn[j4 * 4 + 2], hn[j4 * 4 + 3]);
  }

  // readout partials: pt[t] = sum_j hn[j] * Wp[cbase+j][t]  (Wp rows wave-uniform -> s_load)
  float pt[16] = {0.f};
#pragma unroll
  for (int j = 0; j < 16; ++j) {
    const float* wp = Wp + (size_t)(cbase + j) * TOUT;
#pragma unroll
    for (int t = 0; t < 16; ++t) pt[t] = fmaf(hn[j], wp[t], pt[t]);
  }

  __syncthreads();                  // As2 fully consumed; reuse as exchange buffer
  float* ex = As2;                  // part[w][row][t], stride 17 (bank-spread)
#pragma unroll
  for (int t = 0; t < 16; ++t) ex[wid * 1088 + row * 17 + t] = pt[t];
  __syncthreads();

  int orow = tid >> 2;
  int t4 = (tid & 3) * 4;
  if (rowBase + orow < NN) {
    float4 bb = *(const float4*)(bp + t4);
    float s0 = bb.x, s1 = bb.y, s2 = bb.z, s3 = bb.w;
#pragma unroll
    for (int w = 0; w < 4; ++w) {
      s0 += ex[w * 1088 + orow * 17 + t4 + 0];
      s1 += ex[w * 1088 + orow * 17 + t4 + 1];
      s2 += ex[w * 1088 + orow * 17 + t4 + 2];
      s3 += ex[w * 1088 + orow * 17 + t4 + 3];
    }
    *(float4*)(out + (size_t)(rowBase + orow) * TOUT + t4) = make_float4(s0, s1, s2, s3);
  }
}

extern "C" void kernel_launch(void* const* d_in, const int* in_sizes, int n_in,
                              void* d_out, int out_size, void* d_ws, size_t ws_size,
                              hipStream_t stream) {
  const float* x    = (const float*)d_in[0];
  const int*   ei   = (const int*)d_in[1];
  const float* prev = (const float*)d_in[2];
  const float* W1   = (const float*)d_in[3];
  const float* b1   = (const float*)d_in[4];
  const float* W2   = (const float*)d_in[5];
  const float* b2   = (const float*)d_in[6];
  const float* w_ih = (const float*)d_in[7];
  const float* w_hh = (const float*)d_in[8];
  const float* b_ih = (const float*)d_in[9];
  const float* b_hh = (const float*)d_in[10];
  const float* Wp   = (const float*)d_in[11];
  const float* bp   = (const float*)d_in[12];

  float* out  = (float*)d_out;                 // [NN,16]
  float* hnew = out + (size_t)NN * TOUT;       // [NN,64]

  char* ws = (char*)d_ws;
  float*    dinv    = (float*)(ws + 0);                    // 400,000
  int*      rowptr  = (int*)(ws + 400000);                 // 400,064
  int*      bcur    = (int*)(ws + 800064);                 // 1,564
  int*      bktBase = (int*)(ws + 801664);                 // 1,564
  int*      csr_src = (int*)(ws + 803264);                 // 12,800,000
  __half*   hwsH    = (__half*)(ws + 13603264);            // 12,800,000
  float*    bufB    = (float*)(ws + 26403264);             // 25,600,000 (packed u32 alias)
  float*    bufC    = (float*)(ws + 52003264);             // 25,600,000
  float*    Wcat    = (float*)(ws + 77603264);             // 98,304
  unsigned* packed  = (unsigned*)bufB;

  const int* srcA = ei;
  const int* dstA = ei + NE;

  // ---- CSR build overlapped with layer-1 GEMM + GRU weight prep ----
  k_init<<<(NBUK + 255) / 256, 256, 0, stream>>>(bcur);
  k_megaA<<<NP1BLK + NGEMM1 + NPREP, 256, 0, stream>>>(srcA, dstA, bcur, packed,
                                                       x, W1, hwsH, w_ih, w_hh, Wcat);
  k_scanb<<<1, 512, 0, stream>>>(bcur, bktBase, rowptr);
  k_p2big<<<NBUK, 256, 0, stream>>>(packed, bcur, bktBase, rowptr, dinv, csr_src);

  // ---- GCN layer 1 gather ----
  k_gather<<<(NN + 3) / 4, 256, 0, stream>>>(hwsH, rowptr, csr_src, dinv, b1, bufC);

  // ---- GCN layer 2 ----
  k_gemmh64<<<(NN + 63) / 64, 256, 0, stream>>>(bufC, W2, hwsH);
  k_gather<<<(NN + 3) / 4, 256, 0, stream>>>(hwsH, rowptr, csr_src, dinv, b2, bufC);

  // ---- fused GRU (64-row scalar-weight GEMM + 8-wide a-prefetch + gates + readout) ----
  k_grufused<<<(NN + 63) / 64, 256, 0, stream>>>(bufC, prev, Wcat, b_ih, b_hh, Wp, bp, hnew, out);
}